// Round 1
// baseline (47.838 us; speedup 1.0000x reference)
//
#include <hip/hip_runtime.h>
#include <hip/hip_bf16.h>

// LocallyConnected2d: out[i][j] = sum_{p=0..255} x[i + p/16][j + p%16] * W[i][j][p]
// x: (512,512) f32, W: (497,497,256) f32, out: (497,497) f32.
// Memory-bound: W is 253 MB streamed exactly once. One wave per output
// position: lane l loads W[pos][4l..4l+3] as float4 (coalesced 1 KiB/wave),
// multiplies with the matching 4 x-taps (x is 1 MB, L2-resident), then a
// 64-lane butterfly reduce; lane 0 stores.

constexpr int IN_H  = 512;
constexpr int IN_W  = 512;
constexpr int KH    = 16;
constexpr int KW    = 16;
constexpr int KK    = KH * KW;          // 256
constexpr int OUT_H = IN_H - KH + 1;    // 497
constexpr int OUT_W = IN_W - KW + 1;    // 497
constexpr int NPOS  = OUT_H * OUT_W;    // 247009

__global__ __launch_bounds__(256, 8)
void lc2d_wave_kernel(const float* __restrict__ x,
                      const float* __restrict__ W,
                      float* __restrict__ out) {
    const int lane            = threadIdx.x & 63;
    const int wave_in_block   = threadIdx.x >> 6;
    const int waves_per_block = blockDim.x >> 6;
    const int gwave  = blockIdx.x * waves_per_block + wave_in_block;
    const int nwaves = gridDim.x * waves_per_block;

    const int p0 = lane << 2;       // first of 4 kernel taps for this lane
    const int kh = p0 >> 4;         // p0 / 16  (constant within lane)
    const int kw = p0 & 15;         // p0 % 16  (multiple of 4)

    for (int pos = gwave; pos < NPOS; pos += nwaves) {
        const int i = pos / OUT_W;              // compiler emits magic-mul for const 497
        const int j = pos - i * OUT_W;

        // Coalesced: lane l reads 16 B at (pos*1024 + l*16) — one 1 KiB burst per wave.
        const float4 wv = *reinterpret_cast<const float4*>(W + (size_t)pos * KK + p0);

        const float* xp = x + (i + kh) * IN_W + (j + kw);   // L2-resident
        float s = wv.x * xp[0] + wv.y * xp[1] + wv.z * xp[2] + wv.w * xp[3];

        // 64-lane butterfly reduction.
        #pragma unroll
        for (int off = 32; off; off >>= 1)
            s += __shfl_xor(s, off, 64);

        if (lane == 0) out[pos] = s;
    }
}

extern "C" void kernel_launch(void* const* d_in, const int* in_sizes, int n_in,
                              void* d_out, int out_size, void* d_ws, size_t ws_size,
                              hipStream_t stream) {
    const float* x = (const float*)d_in[0];
    const float* W = (const float*)d_in[1];
    float* out     = (float*)d_out;

    // 2048 blocks x 256 threads = 8192 waves, grid-striding 247009 positions
    // (~30 positions/wave). 8 blocks/CU fills the machine.
    const int threads = 256;
    const int blocks  = 2048;
    lc2d_wave_kernel<<<blocks, threads, 0, stream>>>(x, W, out);
}